// Round 4
// baseline (689.710 us; speedup 1.0000x reference)
//
#include <hip/hip_runtime.h>

// ---------------------------------------------------------------------------
// GCN block: 3 x (GCNConv -> ReLU -> global_mean_pool)
// 9 dispatches. ZERO device-scope atomics in the CSR build (R11: 1.6M device
// atomics rate-limit ~18G/s memory-side regardless of structure); ~200K f32
// pool atomics total (fine at that count). R13 finding: k_agg is fabric-BW
// bound (~3.2 TB/s on random 256B gathers; deeper MLP changed nothing), so
// this round deletes traffic instead: agg + pool + next-layer GEMM fused in
// k_layer — bufH (3 x 25.6MB trips/layer) never exists.
//   k_prep:      graph bounds + WbT transpose/cast + zero out
//   k_phase1:    blocks[0..782) = layer-1 MFMA GEMM (fp32 x, in-reg bf16
//                cast); blocks[782..978) = LDS histogram over 782 coarse
//                buckets (col>>7), plain writes
//   k_scan1:     1024-chunk exclusive scan over the 153K hist matrix
//   k_scat:      inline LDS scan of chunk sums; LDS-atomic ranks; packed
//                (r|c_local<<17, w) records bucket-contiguous (recs=bufB)
//   k_fin:       per bucket: count + weighted degree in LDS, dinv, ptr,
//                self-loop edge at list head, scatter csr.y = w*dinv[c]
//   k_norm2:     csr.y *= dinv[r] over E+N edges
//   k_layer x3:  per block = 128 nodes: (a) wave-per-node gather-aggregate
//                (R8 loop) + bias + relu -> swizzled LDS tile (c4 ^= row&15
//                kills the stride-256B bank conflict on MFMA A-reads);
//                (b) MFMA tile x W_{l+1} -> bufHL' (if HASGEMM);
//                (c) pool partials from LDS, pre-scaled 1/cnt, atomicAdd out;
//                (d) epilogue reuses the tile as staging for coalesced store.
// hist/pre alias csr (dead before k_fin); recs aliases bufB (dead before
// k_layer1 writes bufB).
// ---------------------------------------------------------------------------

typedef short short8 __attribute__((ext_vector_type(8)));   // 8 bf16 (4 VGPR)
typedef float f32x4  __attribute__((ext_vector_type(4)));   // MFMA C/D

__device__ inline unsigned pack_bf16x2(float a, float b) {
    unsigned ua = __float_as_uint(a);
    ua = (ua + 0x7FFFu + ((ua >> 16) & 1u)) >> 16;       // RNE
    unsigned ub = __float_as_uint(b);
    ub = (ub + 0x7FFFu + ((ub >> 16) & 1u)) >> 16;
    return ua | (ub << 16);
}
__device__ inline ushort bf16_1(float a) {
    unsigned ua = __float_as_uint(a);
    return (ushort)((ua + 0x7FFFu + ((ua >> 16) & 1u)) >> 16);
}
__device__ inline float bf_lo(unsigned u) { return __uint_as_float(u << 16); }
__device__ inline float bf_hi(unsigned u) { return __uint_as_float(u & 0xFFFF0000u); }

// u32 index into the 128x64 swizzled h tile: 16B granule XORed with row&15.
__device__ inline int hswz(int row, int c) {
    return row * 64 + ((((c >> 2) ^ (row & 15)) << 2) | (c & 3));
}

// ---- shared device bodies -------------------------------------------------

// One block = 128 rows x 128 cols of hl = H @ W (v_mfma_f32_16x16x32_bf16).
// Wave = 32 rows: 2 m-strips x 8 n-tiles, 64 MFMAs. Global-input variant
// (layer-1: fp32 x with in-register bf16 cast). Epilogue via LDS.
__device__ __forceinline__ void gemm_tile_f32(const float* __restrict__ Hf,
                                              const ushort* __restrict__ WbT,
                                              unsigned* __restrict__ O, int M,
                                              int bid, unsigned* sOut) {
    int lane = threadIdx.x & 63;
    int wv = threadIdx.x >> 6;
    int quad = lane >> 4;
    int mrow = lane & 15;
    int m0 = bid * 128 + wv * 32;
    int r0 = m0 + mrow;
    int r1 = r0 + 16;
    int r0c = r0 < M ? r0 : M - 1;             // clamp loads, guard stores
    int r1c = r1 < M ? r1 : M - 1;

    short8 a0[4], a1[4];
#pragma unroll
    for (int s = 0; s < 4; s++) {              // k-step s covers k in [32s,32s+32)
        const float4* p0 = (const float4*)(Hf + (size_t)r0c * 128 + s * 32 + quad * 8);
        const float4* p1 = (const float4*)(Hf + (size_t)r1c * 128 + s * 32 + quad * 8);
        float4 f0 = p0[0], f1 = p0[1];
        float4 g0 = p1[0], g1 = p1[1];
        union { short8 s8; unsigned u[4]; } t0, t1;
        t0.u[0] = pack_bf16x2(f0.x, f0.y); t0.u[1] = pack_bf16x2(f0.z, f0.w);
        t0.u[2] = pack_bf16x2(f1.x, f1.y); t0.u[3] = pack_bf16x2(f1.z, f1.w);
        t1.u[0] = pack_bf16x2(g0.x, g0.y); t1.u[1] = pack_bf16x2(g0.z, g0.w);
        t1.u[2] = pack_bf16x2(g1.x, g1.y); t1.u[3] = pack_bf16x2(g1.z, g1.w);
        a0[s] = t0.s8; a1[s] = t1.s8;
    }
    f32x4 acc0[8], acc1[8];
#pragma unroll
    for (int t = 0; t < 8; t++) {
        acc0[t] = (f32x4){0.f, 0.f, 0.f, 0.f};
        acc1[t] = (f32x4){0.f, 0.f, 0.f, 0.f};
    }
#pragma unroll
    for (int s = 0; s < 4; s++) {
#pragma unroll
        for (int t = 0; t < 8; t++) {
            short8 b = *(const short8*)(WbT + (t * 16 + mrow) * 128 + s * 32 + quad * 8);
            acc0[t] = __builtin_amdgcn_mfma_f32_16x16x32_bf16(a0[s], b, acc0[t], 0, 0, 0);
            acc1[t] = __builtin_amdgcn_mfma_f32_16x16x32_bf16(a1[s], b, acc1[t], 0, 0, 0);
        }
    }
    // C/D layout: col = lane&15, row = quad*4 + reg.
    ushort* so = (ushort*)(sOut + wv * 32 * 64);
#pragma unroll
    for (int t = 0; t < 8; t++) {
#pragma unroll
        for (int r = 0; r < 4; r++) {
            int lr = quad * 4 + r;
            int c = t * 16 + mrow;
            so[lr * 128 + c] = bf16_1(acc0[t][r]);
            so[(lr + 16) * 128 + c] = bf16_1(acc1[t][r]);
        }
    }
    __syncthreads();
    const unsigned* si = sOut + wv * 32 * 64;
#pragma unroll 8
    for (int r = 0; r < 32; r++) {
        int row = m0 + r;
        if (row < M) O[(size_t)row * 64 + lane] = si[r * 64 + lane];
    }
}

// ---- kernels --------------------------------------------------------------

// Pre-pass: graph bounds + W transpose+cast + zero pooled output.
__global__ void k_prep(const int* __restrict__ batch, int* __restrict__ gb,
                       int G, int N,
                       const float* __restrict__ W0, const float* __restrict__ W1,
                       const float* __restrict__ W2, ushort* __restrict__ WbT,
                       float* __restrict__ outv, int outN) {
    int id = blockIdx.x * blockDim.x + threadIdx.x;
    if (id < outN) outv[id] = 0.f;
    if (id <= G) {
        int lo = 0, hi = N;
        while (lo < hi) { int mid = (lo + hi) >> 1; if (batch[mid] < id) lo = mid + 1; else hi = mid; }
        gb[id] = lo;
    }
    if (id < 3 * 16384) {
        int l = id >> 14;
        const float* W = (l == 0) ? W0 : ((l == 1) ? W1 : W2);
        int id2 = id & 16383;
        int n = id2 & 127, k = id2 >> 7;
        WbT[l * 16384 + n * 128 + k] = bf16_1(W[k * 128 + n]);
    }
}

// Heterogeneous: blocks[0..nbGemm) = layer-1 GEMM (fp32 x, in-reg bf16 cast);
// blocks[nbGemm..nbGemm+nbCount) = LDS histogram over nbGemm (=nbkt) coarse
// buckets (col>>7), 8192 edges/block, plain hist writes. NO global atomics.
__global__ __launch_bounds__(256) void k_phase1(const int* __restrict__ ei,
                                                int* __restrict__ hist, int E,
                                                const float* __restrict__ x,
                                                const ushort* __restrict__ WbT,
                                                unsigned* __restrict__ O, int M,
                                                int nbGemm, int nbCount) {
    __shared__ unsigned sBuf[8192];            // 32 KB (gemm epilogue / hist)
    if (blockIdx.x < nbGemm) {
        gemm_tile_f32(x, WbT, O, M, blockIdx.x, sBuf);
        return;
    }
    int blk = blockIdx.x - nbGemm;
    unsigned* hcnt = sBuf;                     // nbkt (<=784) counters
    int t = threadIdx.x;
    for (int i = t; i < nbGemm; i += 256) hcnt[i] = 0;
    __syncthreads();
    int base = blk * 8192;
    for (int i = t; i < 8192; i += 256) {
        int e = base + i;
        if (e < E) atomicAdd(&hcnt[(unsigned)ei[E + e] >> 7], 1u);  // LDS atomic
    }
    __syncthreads();
    for (int b = t; b < nbGemm; b += 256)      // bucket-major layout
        hist[b * nbCount + blk] = (int)hcnt[b];
}

// 1024-chunk exclusive scan: pre[i] = chunk-local exclusive prefix,
// bsum[chunk] = chunk total. n = nbkt*nbCount (~153K).
__global__ __launch_bounds__(1024) void k_scan1(const int* __restrict__ cnt,
                                                int* __restrict__ pre,
                                                int* __restrict__ bsum, int n) {
    __shared__ int wsum[16];
    int t = threadIdx.x, lane = t & 63, w = t >> 6;
    int i = blockIdx.x * 1024 + t;
    int v = (i < n) ? cnt[i] : 0;
    int x = v;
#pragma unroll
    for (int off = 1; off < 64; off <<= 1) {
        int y = __shfl_up(x, off, 64);
        if (lane >= off) x += y;
    }
    if (lane == 63) wsum[w] = x;
    __syncthreads();
    int woff = 0, tot = 0;
#pragma unroll
    for (int q = 0; q < 16; q++) { int s = wsum[q]; if (q < w) woff += s; tot += s; }
    if (i < n) pre[i] = woff + x - v;
    if (t == 0) bsum[blockIdx.x] = tot;
}

// Pass C: inline LDS scan of the (<=256) chunk sums; per-bucket bases into
// LDS; per-edge rank via LDS atomic; write packed records into bucket-
// contiguous regions. Block 0 also emits bucketStart[].
__global__ __launch_bounds__(256) void k_scat(const int* __restrict__ ei,
                                              const float* __restrict__ ew,
                                              const int* __restrict__ pre,
                                              const int* __restrict__ bsumRaw,
                                              int* __restrict__ bucketStart,
                                              int2* __restrict__ recs,
                                              int E, int nbkt, int nbCount,
                                              int nbScan) {
    __shared__ int sRaw[256];
    __shared__ int sPre[256];
    __shared__ int sWt[4];
    __shared__ int sBase[784];
    __shared__ unsigned rk[784];
    int t = threadIdx.x;
    sRaw[t] = (t < nbScan) ? bsumRaw[t] : 0;
    for (int b = t; b < nbkt; b += 256) rk[b] = 0;
    __syncthreads();
    int lane = t & 63, w2 = t >> 6;
    int v = sRaw[t];
    int x = v;
#pragma unroll
    for (int off = 1; off < 64; off <<= 1) {
        int y = __shfl_up(x, off, 64);
        if (lane >= off) x += y;
    }
    if (lane == 63) sWt[w2] = x;
    __syncthreads();
    int base = 0;
#pragma unroll
    for (int q = 0; q < 4; q++) { if (q < w2) base += sWt[q]; }
    sPre[t] = base + x - v;                    // exclusive prefix of chunk sums
    __syncthreads();
    int blk = blockIdx.x;
    for (int b = t; b < nbkt; b += 256) {
        int f = b * nbCount + blk;
        sBase[b] = pre[f] + sPre[f >> 10];     // this block's base in bucket b
    }
    if (blk == 0) {
        for (int b = t; b <= nbkt; b += 256) {
            if (b == nbkt) bucketStart[b] = E;
            else { int f = b * nbCount; bucketStart[b] = pre[f] + sPre[f >> 10]; }
        }
    }
    __syncthreads();
    int e0 = blk * 8192;
    for (int i = t; i < 8192; i += 256) {
        int e = e0 + i;
        if (e < E) {
            int r = ei[e];
            int c = ei[E + e];
            float w = ew[e];
            int b = (unsigned)c >> 7;
            unsigned rank = atomicAdd(&rk[b], 1u);      // LDS atomic
            int2 rec; rec.x = r | ((c & 127) << 17); rec.y = __float_as_int(w);
            recs[sBase[b] + (int)rank] = rec;
        }
    }
}

// Pass D: one block per bucket (128 nodes). Count + weighted degree in LDS;
// dinv = rsqrt(1 + wdeg); SELF-LOOP edge at each node's list head
// (y = dinv[c]; k_norm2's *dinv[r] makes it dinv^2); ptr includes the self
// slot; then in-bucket scatter of real edges with csr.y = w * dinv[c].
__global__ __launch_bounds__(256) void k_fin(const int2* __restrict__ recs,
                                             const int* __restrict__ bucketStart,
                                             int2* __restrict__ csr,
                                             int* __restrict__ ptrv,
                                             float* __restrict__ dinv,
                                             int N, int nbkt) {
    __shared__ unsigned scnt[128];
    __shared__ float swdeg[128];
    __shared__ float sdinv[128];
    __shared__ unsigned sTot0;
    int t = threadIdx.x;
    int b = blockIdx.x;
    int e0 = bucketStart[b], e1 = bucketStart[b + 1];
    int FB = e0 + b * 128;                     // final base incl. prior selfs
    if (t < 128) { scnt[t] = 0u; swdeg[t] = 0.f; }
    __syncthreads();
    for (int i = e0 + t; i < e1; i += 256) {
        int2 rec = recs[i];
        int cl = (rec.x >> 17) & 127;
        atomicAdd(&scnt[cl], 1u);                       // LDS atomic
        atomicAdd(&swdeg[cl], __int_as_float(rec.y));   // LDS f32 atomic
    }
    __syncthreads();
    unsigned myc = (t < 128) ? scnt[t] : 0u;
    int lane = t & 63, wv = t >> 6;
    unsigned inc = myc;
#pragma unroll
    for (int off = 1; off < 64; off <<= 1) {
        unsigned y = __shfl_up(inc, off, 64);
        if (lane >= off) inc += y;
    }
    if (t == 63) sTot0 = inc;                  // wave-0 total
    __syncthreads();
    unsigned excl = inc - myc + ((wv == 1) ? sTot0 : 0u);
    if (t < 128) {
        float dv = rsqrtf(1.0f + swdeg[t]);
        sdinv[t] = dv;
        scnt[t] = excl + (unsigned)t + 1u;     // scatter cursor (rel. to FB)
        int node = b * 128 + t;
        int start = FB + (int)excl + t;
        if (node < N) {
            ptrv[node] = start;
            dinv[node] = dv;
            int2 sv; sv.x = node; sv.y = __float_as_int(dv);  // self: w=1*dinv[c]
            csr[start] = sv;
        }
    }
    if (b == nbkt - 1 && t == 0) ptrv[N] = e1 + N;  // = E + N
    __syncthreads();
    for (int i = e0 + t; i < e1; i += 256) {
        int2 rec = recs[i];
        int cl = (rec.x >> 17) & 127;
        int r = rec.x & 131071;
        unsigned rank = atomicAdd(&scnt[cl], 1u);       // LDS atomic
        float y = __int_as_float(rec.y) * sdinv[cl];
        int2 mv; mv.x = r; mv.y = __float_as_int(y);
        csr[FB + (int)rank] = mv;
    }
}

// csr.y *= dinv[r] over E+N entries (self edges become dinv^2). Coalesced
// int2 RMW; dinv gathers L2/L3-resident.
__global__ __launch_bounds__(256) void k_norm2(int2* __restrict__ csr,
                                               const float* __restrict__ dinv,
                                               int E) {
    int base = blockIdx.x * 1024 + threadIdx.x;
#pragma unroll
    for (int q = 0; q < 4; q++) {
        int e = base + q * 256;
        if (e < E) {
            int2 m = csr[e];
            m.y = __float_as_int(__int_as_float(m.y) * dinv[m.x]);
            csr[e] = m;
        }
    }
}

// Fused layer: block = 128 dest nodes. (a) wave-per-node gather-aggregate
// (uniform edge list, self at head) + bias + relu into swizzled LDS tile;
// (b) MFMA tile x WbT -> O (next layer's hl); (c) pool partials pre-scaled
// by 1/count, atomicAdd to outp; (d) epilogue reuses tile for coalesced O
// stores. HASGEMM=false: agg + pool only.
template <bool HASGEMM>
__global__ __launch_bounds__(256) void k_layer(const unsigned* __restrict__ HL,
                                               const int* __restrict__ ptr,
                                               const int2* __restrict__ csr,
                                               const float* __restrict__ bias,
                                               const int* __restrict__ gb, int G,
                                               float* __restrict__ outp,
                                               const ushort* __restrict__ WbT,
                                               unsigned* __restrict__ O, int N) {
    __shared__ unsigned hT[8192];              // 128 x 64 u32 swizzled h tile
    __shared__ int2 sM[4 * 64];
    int t = threadIdx.x;
    int lane = t & 63, wv = t >> 6;
    int half = lane >> 5;                 // 0: even edges, 1: odd edges
    int q = lane & 31;                    // features 4q .. 4q+3
    int base = blockIdx.x * 128;
    int2* mbase = &sM[wv * 64];
    const uint2* HL2 = (const uint2*)HL;
    float4 bv = ((const float4*)bias)[q];

    // ---- (a) aggregate: wave wv owns local rows [wv*32, wv*32+32) ----
    for (int i = 0; i < 32; i++) {
        int row = wv * 32 + i;
        int node = base + row;
        if (node >= N) break;
        int e0 = ptr[node], e1 = ptr[node + 1];
        int deg = e1 - e0;                    // includes self edge
        int nbv = deg < 64 ? deg : 64;
        if (lane < nbv) mbase[lane] = csr[e0 + lane];
        float a0 = 0.f, a1 = 0.f, a2 = 0.f, a3 = 0.f;
        int j = half;
        for (; j + 8 <= nbv; j += 8) {                  // 4 pairs in flight
            int2 m[4]; uint2 u[4];
#pragma unroll
            for (int k = 0; k < 4; k++) m[k] = mbase[j + 2 * k];
#pragma unroll
            for (int k = 0; k < 4; k++) u[k] = HL2[(size_t)m[k].x * 32 + q];
#pragma unroll
            for (int k = 0; k < 4; k++) {
                float nv = __int_as_float(m[k].y);
                a0 += nv * bf_lo(u[k].x); a1 += nv * bf_hi(u[k].x);
                a2 += nv * bf_lo(u[k].y); a3 += nv * bf_hi(u[k].y);
            }
        }
        for (; j < nbv; j += 2) {
            int2 m = mbase[j];
            uint2 u = HL2[(size_t)m.x * 32 + q];
            float nv = __int_as_float(m.y);
            a0 += nv * bf_lo(u.x); a1 += nv * bf_hi(u.x);
            a2 += nv * bf_lo(u.y); a3 += nv * bf_hi(u.y);
        }
        for (int e = e0 + 64 + half; e < e1; e += 2) {  // rare high-degree tail
            int2 m = csr[e];
            uint2 u = HL2[(size_t)m.x * 32 + q];
            float nv = __int_as_float(m.y);
            a0 += nv * bf_lo(u.x); a1 += nv * bf_hi(u.x);
            a2 += nv * bf_lo(u.y); a3 += nv * bf_hi(u.y);
        }
        a0 += __shfl_xor(a0, 32, 64);
        a1 += __shfl_xor(a1, 32, 64);
        a2 += __shfl_xor(a2, 32, 64);
        a3 += __shfl_xor(a3, 32, 64);
        if (half == 0) {
            float r0 = fmaxf(a0 + bv.x, 0.f);
            float r1 = fmaxf(a1 + bv.y, 0.f);
            float r2 = fmaxf(a2 + bv.z, 0.f);
            float r3 = fmaxf(a3 + bv.w, 0.f);
            int ix = hswz(row, 2 * q);        // (2q)&3 in {0,2}: pair in-granule
            hT[ix] = pack_bf16x2(r0, r1);
            hT[ix + 1] = pack_bf16x2(r2, r3);
        }
    }
    __syncthreads();

    // ---- (b) MFMA: hl' = hT @ WbT^T (A from swizzled LDS) ----
    f32x4 acc0[8], acc1[8];
    if (HASGEMM) {
        int quad = lane >> 4;
        int mrow = lane & 15;
        int R0 = wv * 32 + mrow, R1 = R0 + 16;
        short8 a0[4], a1[4];
#pragma unroll
        for (int s = 0; s < 4; s++) {
            a0[s] = *(const short8*)&hT[R0 * 64 + (((s * 4 + quad) ^ (R0 & 15)) << 2)];
            a1[s] = *(const short8*)&hT[R1 * 64 + (((s * 4 + quad) ^ (R1 & 15)) << 2)];
        }
#pragma unroll
        for (int k = 0; k < 8; k++) {
            acc0[k] = (f32x4){0.f, 0.f, 0.f, 0.f};
            acc1[k] = (f32x4){0.f, 0.f, 0.f, 0.f};
        }
#pragma unroll
        for (int s = 0; s < 4; s++) {
#pragma unroll
            for (int k = 0; k < 8; k++) {
                short8 b = *(const short8*)(WbT + (k * 16 + mrow) * 128 + s * 32 + quad * 8);
                acc0[k] = __builtin_amdgcn_mfma_f32_16x16x32_bf16(a0[s], b, acc0[k], 0, 0, 0);
                acc1[k] = __builtin_amdgcn_mfma_f32_16x16x32_bf16(a1[s], b, acc1[k], 0, 0, 0);
            }
        }
    }

    // ---- (c) pool partials (reads hT, pre-scaled by 1/count) ----
    if (t < 128) {
        int f = t, c = f >> 1, ch = f & 1;
        int glo = 0, ghi = G;                  // last g with gb[g] <= base
        while (glo < ghi) {
            int mid = (glo + ghi + 1) >> 1;
            if (gb[mid] <= base) glo = mid; else ghi = mid - 1;
        }
        for (int g = glo; g < G; g++) {
            int gs = gb[g];
            if (gs >= base + 128) break;
            int ge = gb[g + 1];
            int r0 = gs > base ? gs : base;
            int r1 = ge < base + 128 ? ge : base + 128;
            if (r1 > N) r1 = N;
            if (r1 <= r0) continue;
            float s = 0.f;
            for (int r = r0; r < r1; r++) {
                unsigned u = hT[hswz(r - base, c)];
                s += ch ? bf_hi(u) : bf_lo(u);
            }
            float cnt = (float)(ge - gs);
            atomicAdd(&outp[g * 128 + f], s / fmaxf(cnt, 1.f));
        }
    }

    // ---- (d) epilogue: reuse hT as staging for coalesced O stores ----
    if (HASGEMM) {
        __syncthreads();                       // pool done reading hT
        int quad = lane >> 4;
        int mrow = lane & 15;
        ushort* so = (ushort*)(hT + wv * 32 * 64);
#pragma unroll
        for (int k = 0; k < 8; k++) {
#pragma unroll
            for (int r = 0; r < 4; r++) {
                int lr = quad * 4 + r;
                int c = k * 16 + mrow;
                so[lr * 128 + c] = bf16_1(acc0[k][r]);
                so[(lr + 16) * 128 + c] = bf16_1(acc1[k][r]);
            }
        }
        __syncthreads();
        const unsigned* si = hT + wv * 32 * 64;
        int m0 = base + wv * 32;
#pragma unroll 8
        for (int r = 0; r < 32; r++) {
            int row = m0 + r;
            if (row < N) O[(size_t)row * 64 + lane] = si[r * 64 + lane];
        }
    }
}

extern "C" void kernel_launch(void* const* d_in, const int* in_sizes, int n_in,
                              void* d_out, int out_size, void* d_ws, size_t ws_size,
                              hipStream_t stream) {
    const float* x     = (const float*)d_in[0];
    const int*   ei    = (const int*)d_in[1];
    const float* ew    = (const float*)d_in[2];
    const int*   batch = (const int*)d_in[3];
    const float* Wt[3] = {(const float*)d_in[4], (const float*)d_in[6], (const float*)d_in[8]};
    const float* bt[3] = {(const float*)d_in[5], (const float*)d_in[7], (const float*)d_in[9]};
    float* out = (float*)d_out;

    const int D = 128;
    const int N = in_sizes[0] / D;       // 100000
    const int E = in_sizes[2];           // 1600000
    const int G = out_size / (3 * D);    // 256

    // workspace carve-up (256 B aligned)
    char* p = (char*)d_ws;
    auto alloc = [&](size_t bytes) {
        void* r = (void*)p;
        p += (bytes + 255) & ~(size_t)255;
        return r;
    };
    int nbkt    = (N + 127) / 128;              // 782 coarse buckets (== nbGemm)
    int nbCount = (E + 8191) / 8192;            // 196 histogram blocks
    int F       = nbkt * nbCount;               // 153272 scan elements
    int nbScan  = (F + 1023) / 1024;            // 150 (<=256 for inline scan)

    int*      ptr    = (int*)alloc((size_t)(N + 1) * 4);
    int*      bsum   = (int*)alloc((size_t)256 * 4);
    int*      gb     = (int*)alloc((size_t)(G + 1) * 4);
    int*      bstart = (int*)alloc((size_t)(nbkt + 1) * 4);
    float*    dinv   = (float*)alloc((size_t)N * 4);
    ushort*   WbT    = (ushort*)alloc((size_t)3 * 16384 * 2);
    int2*     csr    = (int2*)alloc((size_t)(E + N) * 8);     // incl. selfs
    unsigned* bufA   = (unsigned*)alloc((size_t)N * 64 * 4);  // hl ping
    unsigned* bufB   = (unsigned*)alloc((size_t)N * 64 * 4);  // hl pong
    // aliases: hist+pre live only before k_fin writes csr; recs dead before
    // k_layer1 writes bufB.
    int*  hist = (int*)csr;                    // F ints (613 KB)
    int*  pre  = hist + F;                     // F ints
    int2* recs = (int2*)bufB;                  // E int2 (12.8 MB)

    int nbGemm = nbkt;                          // 782 gemm blocks
    int prepWork = 3 * G * D;                   // 98304 (covers WbT + gb too)

    k_prep<<<(prepWork + 255) / 256, 256, 0, stream>>>(batch, gb, G, N,
                                                       Wt[0], Wt[1], Wt[2], WbT,
                                                       out, 3 * G * D);
    // layer-1 GEMM fused with the histogram pass (independent inputs)
    k_phase1<<<nbGemm + nbCount, 256, 0, stream>>>(ei, hist, E, x, WbT,
                                                   bufA, N, nbGemm, nbCount);
    k_scan1<<<nbScan, 1024, 0, stream>>>(hist, pre, bsum, F);
    k_scat<<<nbCount, 256, 0, stream>>>(ei, ew, pre, bsum, bstart, recs,
                                        E, nbkt, nbCount, nbScan);
    k_fin<<<nbkt, 256, 0, stream>>>(recs, bstart, csr, ptr, dinv, N, nbkt);
    k_norm2<<<(E + N + 1023) / 1024, 256, 0, stream>>>(csr, dinv, E + N);

    // fused layers: agg + pool_l + gemm_{l+1}
    k_layer<true><<<nbkt, 256, 0, stream>>>(bufA, ptr, csr, bt[0], gb, G,
                                            out + 0 * (size_t)G * D,
                                            WbT + 16384, bufB, N);
    k_layer<true><<<nbkt, 256, 0, stream>>>(bufB, ptr, csr, bt[1], gb, G,
                                            out + 1 * (size_t)G * D,
                                            WbT + 2 * 16384, bufA, N);
    k_layer<false><<<nbkt, 256, 0, stream>>>(bufA, ptr, csr, bt[2], gb, G,
                                             out + 2 * (size_t)G * D,
                                             nullptr, nullptr, N);
}

// Round 5
// 513.176 us; speedup vs baseline: 1.3440x; 1.3440x over previous
//
#include <hip/hip_runtime.h>

// ---------------------------------------------------------------------------
// GCN block: 3 x (GCNConv -> ReLU -> global_mean_pool)
// 11 dispatches. ZERO device-scope atomics in the CSR build (R11: 1.6M
// device atomics rate-limit ~18G/s memory-side regardless of structure).
// R13: k_agg is fabric-BW bound (~410MB demand @ ~6.1 TB/s = its roofline;
// deeper MLP changed nothing). R14: fusing agg+gemm+pool into block-owned
// 128-node tiles collapsed gather parallelism (3128 waves for 100K node
// tasks -> 1.13 TB/s, 194us/layer) — the gather MUST stay wave-per-node
// with a maximal grid. This round: proven split structure + k_norm2 folded
// into k_agg layer 1 (normalize-on-first-use with write-back; each csr
// entry is owned by exactly one wave, so the RMW is race-free).
//   k_prep:      graph bounds + WbT transpose/cast
//   k_phase1:    blocks[0..782) = layer-1 MFMA GEMM (fp32 x, in-reg bf16
//                cast); blocks[782..978) = LDS histogram over 782 coarse
//                buckets (col>>7), plain writes
//   k_scan1:     1024-chunk exclusive scan over the 153K hist matrix
//   k_scat:      inline LDS scan of chunk sums; LDS-atomic ranks; packed
//                (r|c_local<<17, w) records bucket-contiguous (recs=bufB)
//   k_fin:       per bucket: count + weighted degree in LDS, dinv, ptr,
//                self-loop edge at list head, scatter csr.y = w*dinv[c]
//   per layer:   k_agg<NORM> (wave-per-node paired-edge gather, R8 loop;
//                NORM=true on layer 1: csr.y *= dinv[src], written back) ->
//                k_gemm_pool (next-layer GEMM + prev-layer pool fused;
//                final call pool-only, nbGemm=0)
// hist/pre alias csr (dead before k_fin); recs aliases bufB (dead before
// k_agg L1 writes bufB).
// ---------------------------------------------------------------------------

typedef short short8 __attribute__((ext_vector_type(8)));   // 8 bf16 (4 VGPR)
typedef float f32x4  __attribute__((ext_vector_type(4)));   // MFMA C/D

__device__ inline unsigned pack_bf16x2(float a, float b) {
    unsigned ua = __float_as_uint(a);
    ua = (ua + 0x7FFFu + ((ua >> 16) & 1u)) >> 16;       // RNE
    unsigned ub = __float_as_uint(b);
    ub = (ub + 0x7FFFu + ((ub >> 16) & 1u)) >> 16;
    return ua | (ub << 16);
}
__device__ inline ushort bf16_1(float a) {
    unsigned ua = __float_as_uint(a);
    return (ushort)((ua + 0x7FFFu + ((ua >> 16) & 1u)) >> 16);
}
__device__ inline float bf_lo(unsigned u) { return __uint_as_float(u << 16); }
__device__ inline float bf_hi(unsigned u) { return __uint_as_float(u & 0xFFFF0000u); }

// ---- shared device bodies -------------------------------------------------

// One block = 128 rows x 128 cols of hl = H @ W (v_mfma_f32_16x16x32_bf16).
// Wave = 32 rows: 2 m-strips x 8 n-tiles, 64 MFMAs. A-frag 16B/lane
// contiguous (F32IN: 32B fp32 -> in-register bf16 cast). B from WbT[n][k].
// Epilogue via LDS (sOut, 8192 u32) -> coalesced u32 stores.
template <bool F32IN>
__device__ __forceinline__ void gemm_tile(const void* __restrict__ Hin,
                                          const ushort* __restrict__ WbT,
                                          unsigned* __restrict__ O, int M,
                                          int bid, unsigned* sOut) {
    int lane = threadIdx.x & 63;
    int wv = threadIdx.x >> 6;
    int quad = lane >> 4;
    int mrow = lane & 15;
    int m0 = bid * 128 + wv * 32;
    int r0 = m0 + mrow;
    int r1 = r0 + 16;
    int r0c = r0 < M ? r0 : M - 1;             // clamp loads, guard stores
    int r1c = r1 < M ? r1 : M - 1;

    short8 a0[4], a1[4];
    if (F32IN) {
        const float* Hf = (const float*)Hin;
#pragma unroll
        for (int s = 0; s < 4; s++) {          // k-step s covers k in [32s,32s+32)
            const float4* p0 = (const float4*)(Hf + (size_t)r0c * 128 + s * 32 + quad * 8);
            const float4* p1 = (const float4*)(Hf + (size_t)r1c * 128 + s * 32 + quad * 8);
            float4 f0 = p0[0], f1 = p0[1];
            float4 g0 = p1[0], g1 = p1[1];
            union { short8 s8; unsigned u[4]; } t0, t1;
            t0.u[0] = pack_bf16x2(f0.x, f0.y); t0.u[1] = pack_bf16x2(f0.z, f0.w);
            t0.u[2] = pack_bf16x2(f1.x, f1.y); t0.u[3] = pack_bf16x2(f1.z, f1.w);
            t1.u[0] = pack_bf16x2(g0.x, g0.y); t1.u[1] = pack_bf16x2(g0.z, g0.w);
            t1.u[2] = pack_bf16x2(g1.x, g1.y); t1.u[3] = pack_bf16x2(g1.z, g1.w);
            a0[s] = t0.s8; a1[s] = t1.s8;
        }
    } else {
        const unsigned* Hb = (const unsigned*)Hin;
#pragma unroll
        for (int s = 0; s < 4; s++) {
            a0[s] = *(const short8*)(Hb + (size_t)r0c * 64 + s * 16 + quad * 4);
            a1[s] = *(const short8*)(Hb + (size_t)r1c * 64 + s * 16 + quad * 4);
        }
    }
    f32x4 acc0[8], acc1[8];
#pragma unroll
    for (int t = 0; t < 8; t++) {
        acc0[t] = (f32x4){0.f, 0.f, 0.f, 0.f};
        acc1[t] = (f32x4){0.f, 0.f, 0.f, 0.f};
    }
#pragma unroll
    for (int s = 0; s < 4; s++) {
#pragma unroll
        for (int t = 0; t < 8; t++) {
            short8 b = *(const short8*)(WbT + (t * 16 + mrow) * 128 + s * 32 + quad * 8);
            acc0[t] = __builtin_amdgcn_mfma_f32_16x16x32_bf16(a0[s], b, acc0[t], 0, 0, 0);
            acc1[t] = __builtin_amdgcn_mfma_f32_16x16x32_bf16(a1[s], b, acc1[t], 0, 0, 0);
        }
    }
    // C/D layout: col = lane&15, row = quad*4 + reg.
    ushort* so = (ushort*)(sOut + wv * 32 * 64);
#pragma unroll
    for (int t = 0; t < 8; t++) {
#pragma unroll
        for (int r = 0; r < 4; r++) {
            int lr = quad * 4 + r;
            int c = t * 16 + mrow;
            so[lr * 128 + c] = bf16_1(acc0[t][r]);
            so[(lr + 16) * 128 + c] = bf16_1(acc1[t][r]);
        }
    }
    __syncthreads();
    const unsigned* si = sOut + wv * 32 * 64;
#pragma unroll 8
    for (int r = 0; r < 32; r++) {
        int row = m0 + r;
        if (row < M) O[(size_t)row * 64 + lane] = si[r * 64 + lane];
    }
}

// One block per graph: stream the sorted node segment, 4 waves stride it,
// LDS-combine (part = 512 floats), divide by count, write. No atomics.
__device__ __forceinline__ void pool_tile(const unsigned* __restrict__ HB,
                                          const int* __restrict__ gb,
                                          float* __restrict__ outp, int g,
                                          float* part) {
    int lane = threadIdx.x & 63, w = threadIdx.x >> 6;
    int s = gb[g], e = gb[g + 1];
    float ax = 0.f, ay = 0.f;
    for (int i = s + w; i < e; i += 4) {
        unsigned u = HB[(size_t)i * 64 + lane];
        ax += bf_lo(u); ay += bf_hi(u);
    }
    part[w * 128 + lane * 2] = ax;
    part[w * 128 + lane * 2 + 1] = ay;
    __syncthreads();
    if (threadIdx.x < 128) {
        float sum = part[threadIdx.x] + part[128 + threadIdx.x]
                  + part[256 + threadIdx.x] + part[384 + threadIdx.x];
        float c = (float)(e - s);
        outp[g * 128 + threadIdx.x] = sum / fmaxf(c, 1.0f);
    }
}

// ---- kernels --------------------------------------------------------------

// Pre-pass: graph bounds + W transpose+cast.
__global__ void k_prep(const int* __restrict__ batch, int* __restrict__ gb,
                       int G, int N,
                       const float* __restrict__ W0, const float* __restrict__ W1,
                       const float* __restrict__ W2, ushort* __restrict__ WbT) {
    int id = blockIdx.x * blockDim.x + threadIdx.x;
    if (id <= G) {
        int lo = 0, hi = N;
        while (lo < hi) { int mid = (lo + hi) >> 1; if (batch[mid] < id) lo = mid + 1; else hi = mid; }
        gb[id] = lo;
    }
    if (id < 3 * 16384) {
        int l = id >> 14;
        const float* W = (l == 0) ? W0 : ((l == 1) ? W1 : W2);
        int id2 = id & 16383;
        int n = id2 & 127, k = id2 >> 7;
        WbT[l * 16384 + n * 128 + k] = bf16_1(W[k * 128 + n]);
    }
}

// Heterogeneous: blocks[0..nbGemm) = layer-1 GEMM (fp32 x, in-reg bf16 cast);
// blocks[nbGemm..nbGemm+nbCount) = LDS histogram over nbGemm (=nbkt) coarse
// buckets (col>>7), 8192 edges/block, plain hist writes. NO global atomics.
__global__ __launch_bounds__(256) void k_phase1(const int* __restrict__ ei,
                                                int* __restrict__ hist, int E,
                                                const float* __restrict__ x,
                                                const ushort* __restrict__ WbT,
                                                unsigned* __restrict__ O, int M,
                                                int nbGemm, int nbCount) {
    __shared__ unsigned sBuf[8192];            // 32 KB (gemm epilogue / hist)
    if (blockIdx.x < nbGemm) {
        gemm_tile<true>(x, WbT, O, M, blockIdx.x, sBuf);
        return;
    }
    int blk = blockIdx.x - nbGemm;
    unsigned* hcnt = sBuf;                     // nbkt (<=784) counters
    int t = threadIdx.x;
    for (int i = t; i < nbGemm; i += 256) hcnt[i] = 0;
    __syncthreads();
    int base = blk * 8192;
    for (int i = t; i < 8192; i += 256) {
        int e = base + i;
        if (e < E) atomicAdd(&hcnt[(unsigned)ei[E + e] >> 7], 1u);  // LDS atomic
    }
    __syncthreads();
    for (int b = t; b < nbGemm; b += 256)      // bucket-major layout
        hist[b * nbCount + blk] = (int)hcnt[b];
}

// 1024-chunk exclusive scan: pre[i] = chunk-local exclusive prefix,
// bsum[chunk] = chunk total. n = nbkt*nbCount (~153K).
__global__ __launch_bounds__(1024) void k_scan1(const int* __restrict__ cnt,
                                                int* __restrict__ pre,
                                                int* __restrict__ bsum, int n) {
    __shared__ int wsum[16];
    int t = threadIdx.x, lane = t & 63, w = t >> 6;
    int i = blockIdx.x * 1024 + t;
    int v = (i < n) ? cnt[i] : 0;
    int x = v;
#pragma unroll
    for (int off = 1; off < 64; off <<= 1) {
        int y = __shfl_up(x, off, 64);
        if (lane >= off) x += y;
    }
    if (lane == 63) wsum[w] = x;
    __syncthreads();
    int woff = 0, tot = 0;
#pragma unroll
    for (int q = 0; q < 16; q++) { int s = wsum[q]; if (q < w) woff += s; tot += s; }
    if (i < n) pre[i] = woff + x - v;
    if (t == 0) bsum[blockIdx.x] = tot;
}

// Pass C: inline LDS scan of the (<=256) chunk sums; per-bucket bases into
// LDS; per-edge rank via LDS atomic; write packed records into bucket-
// contiguous regions. Block 0 also emits bucketStart[].
__global__ __launch_bounds__(256) void k_scat(const int* __restrict__ ei,
                                              const float* __restrict__ ew,
                                              const int* __restrict__ pre,
                                              const int* __restrict__ bsumRaw,
                                              int* __restrict__ bucketStart,
                                              int2* __restrict__ recs,
                                              int E, int nbkt, int nbCount,
                                              int nbScan) {
    __shared__ int sRaw[256];
    __shared__ int sPre[256];
    __shared__ int sWt[4];
    __shared__ int sBase[784];
    __shared__ unsigned rk[784];
    int t = threadIdx.x;
    sRaw[t] = (t < nbScan) ? bsumRaw[t] : 0;
    for (int b = t; b < nbkt; b += 256) rk[b] = 0;
    __syncthreads();
    int lane = t & 63, w2 = t >> 6;
    int v = sRaw[t];
    int x = v;
#pragma unroll
    for (int off = 1; off < 64; off <<= 1) {
        int y = __shfl_up(x, off, 64);
        if (lane >= off) x += y;
    }
    if (lane == 63) sWt[w2] = x;
    __syncthreads();
    int base = 0;
#pragma unroll
    for (int q = 0; q < 4; q++) { if (q < w2) base += sWt[q]; }
    sPre[t] = base + x - v;                    // exclusive prefix of chunk sums
    __syncthreads();
    int blk = blockIdx.x;
    for (int b = t; b < nbkt; b += 256) {
        int f = b * nbCount + blk;
        sBase[b] = pre[f] + sPre[f >> 10];     // this block's base in bucket b
    }
    if (blk == 0) {
        for (int b = t; b <= nbkt; b += 256) {
            if (b == nbkt) bucketStart[b] = E;
            else { int f = b * nbCount; bucketStart[b] = pre[f] + sPre[f >> 10]; }
        }
    }
    __syncthreads();
    int e0 = blk * 8192;
    for (int i = t; i < 8192; i += 256) {
        int e = e0 + i;
        if (e < E) {
            int r = ei[e];
            int c = ei[E + e];
            float w = ew[e];
            int b = (unsigned)c >> 7;
            unsigned rank = atomicAdd(&rk[b], 1u);      // LDS atomic
            int2 rec; rec.x = r | ((c & 127) << 17); rec.y = __float_as_int(w);
            recs[sBase[b] + (int)rank] = rec;
        }
    }
}

// Pass D: one block per bucket (128 nodes). Count + weighted degree in LDS;
// dinv = rsqrt(1 + wdeg); SELF-LOOP edge at each node's list head
// (y = dinv[c]; k_agg L1's *dinv[src] makes it dinv^2); ptr includes the
// self slot; then in-bucket scatter of real edges with csr.y = w * dinv[c].
__global__ __launch_bounds__(256) void k_fin(const int2* __restrict__ recs,
                                             const int* __restrict__ bucketStart,
                                             int2* __restrict__ csr,
                                             int* __restrict__ ptrv,
                                             float* __restrict__ dinv,
                                             int N, int nbkt) {
    __shared__ unsigned scnt[128];
    __shared__ float swdeg[128];
    __shared__ float sdinv[128];
    __shared__ unsigned sTot0;
    int t = threadIdx.x;
    int b = blockIdx.x;
    int e0 = bucketStart[b], e1 = bucketStart[b + 1];
    int FB = e0 + b * 128;                     // final base incl. prior selfs
    if (t < 128) { scnt[t] = 0u; swdeg[t] = 0.f; }
    __syncthreads();
    for (int i = e0 + t; i < e1; i += 256) {
        int2 rec = recs[i];
        int cl = (rec.x >> 17) & 127;
        atomicAdd(&scnt[cl], 1u);                       // LDS atomic
        atomicAdd(&swdeg[cl], __int_as_float(rec.y));   // LDS f32 atomic
    }
    __syncthreads();
    unsigned myc = (t < 128) ? scnt[t] : 0u;
    int lane = t & 63, wv = t >> 6;
    unsigned inc = myc;
#pragma unroll
    for (int off = 1; off < 64; off <<= 1) {
        unsigned y = __shfl_up(inc, off, 64);
        if (lane >= off) inc += y;
    }
    if (t == 63) sTot0 = inc;                  // wave-0 total
    __syncthreads();
    unsigned excl = inc - myc + ((wv == 1) ? sTot0 : 0u);
    if (t < 128) {
        float dv = rsqrtf(1.0f + swdeg[t]);
        sdinv[t] = dv;
        scnt[t] = excl + (unsigned)t + 1u;     // scatter cursor (rel. to FB)
        int node = b * 128 + t;
        int start = FB + (int)excl + t;
        if (node < N) {
            ptrv[node] = start;
            dinv[node] = dv;
            int2 sv; sv.x = node; sv.y = __float_as_int(dv);  // self: w=1*dinv[c]
            csr[start] = sv;
        }
    }
    if (b == nbkt - 1 && t == 0) ptrv[N] = e1 + N;  // = E + N
    __syncthreads();
    for (int i = e0 + t; i < e1; i += 256) {
        int2 rec = recs[i];
        int cl = (rec.x >> 17) & 127;
        int r = rec.x & 131071;
        unsigned rank = atomicAdd(&scnt[cl], 1u);       // LDS atomic
        float y = __int_as_float(rec.y) * sdinv[cl];
        int2 mv; mv.x = r; mv.y = __float_as_int(y);
        csr[FB + (int)rank] = mv;
    }
}

// One wave per node, uniform edge list (self-loop is edge 0). Paired-edge
// R8-proven loop (4 pairs = 8 edges/iter). NORM (layer 1 only): csr.y still
// lacks the *dinv[src] factor — apply it on first use and WRITE IT BACK
// (each csr entry is read/written by exactly one wave; dinv is a 400KB
// L2-resident table). Layers 2/3 read the finalized values (NORM=false).
template <bool NORM>
__global__ __launch_bounds__(256) void k_agg(const unsigned* __restrict__ HL,
                                             const int* __restrict__ ptr,
                                             int2* __restrict__ csr,
                                             const float* __restrict__ dinv,
                                             const float* __restrict__ bias,
                                             unsigned* __restrict__ Hout, int M) {
    __shared__ int2 sM[4 * 64];
    int node = (int)((blockIdx.x * blockDim.x + threadIdx.x) >> 6);
    if (node >= M) return;
    int lane = threadIdx.x & 63;
    int half = lane >> 5;                 // 0: even edges, 1: odd edges
    int q = lane & 31;                    // features 4q .. 4q+3
    int2* mbase = &sM[(threadIdx.x >> 6) * 64];
    int e0 = ptr[node], e1 = ptr[node + 1];
    int deg = e1 - e0;                    // includes self edge
    int nbv = deg < 64 ? deg : 64;
    if (lane < nbv) {
        int2 m = csr[e0 + lane];          // one coalesced load
        if (NORM) {
            m.y = __float_as_int(__int_as_float(m.y) * dinv[m.x]);
            csr[e0 + lane] = m;           // finalize for layers 2/3
        }
        mbase[lane] = m;
    }
    const uint2* HL2 = (const uint2*)HL;            // row = 32 uint2
    float a0 = 0.f, a1 = 0.f, a2 = 0.f, a3 = 0.f;
    int j = half;
    for (; j + 8 <= nbv; j += 8) {                  // 4 pairs in flight
        int2 m[4]; uint2 u[4];
#pragma unroll
        for (int t = 0; t < 4; t++) m[t] = mbase[j + 2 * t];
#pragma unroll
        for (int t = 0; t < 4; t++) u[t] = HL2[(size_t)m[t].x * 32 + q];
#pragma unroll
        for (int t = 0; t < 4; t++) {
            float nv = __int_as_float(m[t].y);
            a0 += nv * bf_lo(u[t].x); a1 += nv * bf_hi(u[t].x);
            a2 += nv * bf_lo(u[t].y); a3 += nv * bf_hi(u[t].y);
        }
    }
    for (; j < nbv; j += 2) {
        int2 m = mbase[j];
        uint2 u = HL2[(size_t)m.x * 32 + q];
        float nv = __int_as_float(m.y);
        a0 += nv * bf_lo(u.x); a1 += nv * bf_hi(u.x);
        a2 += nv * bf_lo(u.y); a3 += nv * bf_hi(u.y);
    }
    for (int e = e0 + 64 + half; e < e1; e += 2) {  // rare high-degree tail
        int2 m = csr[e];                  // each tail edge visited exactly once
        if (NORM) {
            m.y = __float_as_int(__int_as_float(m.y) * dinv[m.x]);
            csr[e] = m;
        }
        uint2 u = HL2[(size_t)m.x * 32 + q];
        float nv = __int_as_float(m.y);
        a0 += nv * bf_lo(u.x); a1 += nv * bf_hi(u.x);
        a2 += nv * bf_lo(u.y); a3 += nv * bf_hi(u.y);
    }
    a0 += __shfl_xor(a0, 32, 64);
    a1 += __shfl_xor(a1, 32, 64);
    a2 += __shfl_xor(a2, 32, 64);
    a3 += __shfl_xor(a3, 32, 64);
    float4 bv = ((const float4*)bias)[q];
    float r0 = fmaxf(a0 + bv.x, 0.f);
    float r1 = fmaxf(a1 + bv.y, 0.f);
    float r2 = fmaxf(a2 + bv.z, 0.f);
    float r3 = fmaxf(a3 + bv.w, 0.f);
    if (half == 0) {
        uint2 pv;
        pv.x = pack_bf16x2(r0, r1);
        pv.y = pack_bf16x2(r2, r3);
        ((uint2*)(Hout + (size_t)node * 64))[q] = pv;
    }
}

// Heterogeneous: blocks[0..nbGemm) = next-layer GEMM reading Hb;
// blocks[nbGemm..nbGemm+G) = pool of the SAME Hb into outp (both depend only
// on the preceding agg). nbGemm=0 -> pool-only (final layer).
__global__ __launch_bounds__(256) void k_gemm_pool(const unsigned* __restrict__ Hb,
                                                   const ushort* __restrict__ WbT,
                                                   unsigned* __restrict__ O, int M,
                                                   const int* __restrict__ gb,
                                                   float* __restrict__ outp,
                                                   int nbGemm) {
    __shared__ unsigned sBuf[8192];            // gemm epilogue / pool partials
    if (blockIdx.x < nbGemm) {
        gemm_tile<false>(Hb, WbT, O, M, blockIdx.x, sBuf);
        return;
    }
    pool_tile(Hb, gb, outp, blockIdx.x - nbGemm, (float*)sBuf);
}

extern "C" void kernel_launch(void* const* d_in, const int* in_sizes, int n_in,
                              void* d_out, int out_size, void* d_ws, size_t ws_size,
                              hipStream_t stream) {
    const float* x     = (const float*)d_in[0];
    const int*   ei    = (const int*)d_in[1];
    const float* ew    = (const float*)d_in[2];
    const int*   batch = (const int*)d_in[3];
    const float* Wt[3] = {(const float*)d_in[4], (const float*)d_in[6], (const float*)d_in[8]};
    const float* bt[3] = {(const float*)d_in[5], (const float*)d_in[7], (const float*)d_in[9]};
    float* out = (float*)d_out;

    const int D = 128;
    const int N = in_sizes[0] / D;       // 100000
    const int E = in_sizes[2];           // 1600000
    const int G = out_size / (3 * D);    // 256

    // workspace carve-up (256 B aligned)
    char* p = (char*)d_ws;
    auto alloc = [&](size_t bytes) {
        void* r = (void*)p;
        p += (bytes + 255) & ~(size_t)255;
        return r;
    };
    int nbkt    = (N + 127) / 128;              // 782 coarse buckets (== nbGemm)
    int nbCount = (E + 8191) / 8192;            // 196 histogram blocks
    int F       = nbkt * nbCount;               // 153272 scan elements
    int nbScan  = (F + 1023) / 1024;            // 150 (<=256 for inline scan)

    int*      ptr    = (int*)alloc((size_t)(N + 1) * 4);
    int*      bsum   = (int*)alloc((size_t)256 * 4);
    int*      gb     = (int*)alloc((size_t)(G + 1) * 4);
    int*      bstart = (int*)alloc((size_t)(nbkt + 1) * 4);
    float*    dinv   = (float*)alloc((size_t)N * 4);
    ushort*   WbT    = (ushort*)alloc((size_t)3 * 16384 * 2);
    int2*     csr    = (int2*)alloc((size_t)(E + N) * 8);     // incl. selfs
    unsigned* bufA   = (unsigned*)alloc((size_t)N * 64 * 4);  // hl ping
    unsigned* bufB   = (unsigned*)alloc((size_t)N * 64 * 4);  // h / hl pong
    // aliases: hist+pre live only before k_fin writes csr; recs dead before
    // k_agg L1 writes bufB.
    int*  hist = (int*)csr;                    // F ints (613 KB)
    int*  pre  = hist + F;                     // F ints
    int2* recs = (int2*)bufB;                  // E int2 (12.8 MB)

    int nbGemm = nbkt;                          // 782 gemm blocks
    int prepWork = 3 * 16384;

    k_prep<<<(prepWork + 255) / 256, 256, 0, stream>>>(batch, gb, G, N,
                                                       Wt[0], Wt[1], Wt[2], WbT);
    // layer-1 GEMM fused with the histogram pass (independent inputs)
    k_phase1<<<nbGemm + nbCount, 256, 0, stream>>>(ei, hist, E, x, WbT,
                                                   bufA, N, nbGemm, nbCount);
    k_scan1<<<nbScan, 1024, 0, stream>>>(hist, pre, bsum, F);
    k_scat<<<nbCount, 256, 0, stream>>>(ei, ew, pre, bsum, bstart, recs,
                                        E, nbkt, nbCount, nbScan);
    k_fin<<<nbkt, 256, 0, stream>>>(recs, bstart, csr, ptr, dinv, N, nbkt);

    // L1 aggregate (finalizes csr.y *= dinv[src] in-flight), then fused
    // (gemm_{l+1} + pool_l), final pool-only.
    k_agg<true><<<(N + 3) / 4, 256, 0, stream>>>(bufA, ptr, csr, dinv, bt[0],
                                                 bufB, N);
    k_gemm_pool<<<nbGemm + G, 256, 0, stream>>>(bufB, WbT + 16384, bufA, N,
                                                gb, out + 0 * (size_t)G * D, nbGemm);
    k_agg<false><<<(N + 3) / 4, 256, 0, stream>>>(bufA, ptr, csr, dinv, bt[1],
                                                  bufB, N);
    k_gemm_pool<<<nbGemm + G, 256, 0, stream>>>(bufB, WbT + 2 * 16384, bufA, N,
                                                gb, out + 1 * (size_t)G * D, nbGemm);
    k_agg<false><<<(N + 3) / 4, 256, 0, stream>>>(bufA, ptr, csr, dinv, bt[2],
                                                  bufB, N);
    k_gemm_pool<<<G, 256, 0, stream>>>(bufB, WbT, nullptr, 0,
                                       gb, out + 2 * (size_t)G * D, 0);
}

// Round 6
// 509.572 us; speedup vs baseline: 1.3535x; 1.0071x over previous
//
#include <hip/hip_runtime.h>

// ---------------------------------------------------------------------------
// GCN block: 3 x (GCNConv -> ReLU -> global_mean_pool)
// 11 dispatches. ZERO device-scope atomics in the CSR build (R11: 1.6M
// device atomics rate-limit ~18G/s memory-side regardless of structure).
// R13: k_agg gather traffic is irreducible (~435MB/layer random 256B rows);
// R14: gather must stay wave-per-node, maximal grid. R15: norm2 folded into
// k_agg L1 (write-back; race-free). R16 (this round): k_agg re-issued as
// QUAD-EDGE uint4 gather — lane=(grp 0..3, q 0..15), one wave-load covers 4
// edges (VMEM insts halve), 8 features/lane (VALU per edge ~halves); csr.x
// pre-scaled to uint4-row index (node*16) so per-load addressing is one
// 32-bit add (R5 counters: VALUBusy 46% ~= 32us of 70 — issue-count-bound
// component, not bytes).
//   k_prep:      graph bounds + WbT transpose/cast
//   k_phase1:    blocks[0..782) = layer-1 MFMA GEMM (fp32 x, in-reg bf16
//                cast); blocks[782..978) = LDS histogram over 782 coarse
//                buckets (col>>7), plain writes
//   k_scan1:     1024-chunk exclusive scan over the 153K hist matrix
//   k_scat:      inline LDS scan of chunk sums; LDS-atomic ranks; packed
//                (r|c_local<<17, w) records bucket-contiguous (recs=bufB)
//   k_fin:       per bucket: count + weighted degree in LDS, dinv, ptr,
//                self-loop edge at list head, csr.x = node*16, csr.y =
//                w*dinv[c]
//   per layer:   k_agg<NORM> (wave-per-node quad-edge gather; NORM=true on
//                layer 1: csr.y *= dinv[src], written back) ->
//                k_gemm_pool (next-layer GEMM + prev-layer pool fused;
//                final call pool-only, nbGemm=0)
// hist/pre alias csr (dead before k_fin); recs aliases bufB (dead before
// k_agg L1 writes bufB).
// ---------------------------------------------------------------------------

typedef short short8 __attribute__((ext_vector_type(8)));   // 8 bf16 (4 VGPR)
typedef float f32x4  __attribute__((ext_vector_type(4)));   // MFMA C/D

__device__ inline unsigned pack_bf16x2(float a, float b) {
    unsigned ua = __float_as_uint(a);
    ua = (ua + 0x7FFFu + ((ua >> 16) & 1u)) >> 16;       // RNE
    unsigned ub = __float_as_uint(b);
    ub = (ub + 0x7FFFu + ((ub >> 16) & 1u)) >> 16;
    return ua | (ub << 16);
}
__device__ inline ushort bf16_1(float a) {
    unsigned ua = __float_as_uint(a);
    return (ushort)((ua + 0x7FFFu + ((ua >> 16) & 1u)) >> 16);
}
__device__ inline float bf_lo(unsigned u) { return __uint_as_float(u << 16); }
__device__ inline float bf_hi(unsigned u) { return __uint_as_float(u & 0xFFFF0000u); }

// ---- shared device bodies -------------------------------------------------

// One block = 128 rows x 128 cols of hl = H @ W (v_mfma_f32_16x16x32_bf16).
// Wave = 32 rows: 2 m-strips x 8 n-tiles, 64 MFMAs. A-frag 16B/lane
// contiguous (F32IN: 32B fp32 -> in-register bf16 cast). B from WbT[n][k].
// Epilogue via LDS (sOut, 8192 u32) -> coalesced u32 stores.
template <bool F32IN>
__device__ __forceinline__ void gemm_tile(const void* __restrict__ Hin,
                                          const ushort* __restrict__ WbT,
                                          unsigned* __restrict__ O, int M,
                                          int bid, unsigned* sOut) {
    int lane = threadIdx.x & 63;
    int wv = threadIdx.x >> 6;
    int quad = lane >> 4;
    int mrow = lane & 15;
    int m0 = bid * 128 + wv * 32;
    int r0 = m0 + mrow;
    int r1 = r0 + 16;
    int r0c = r0 < M ? r0 : M - 1;             // clamp loads, guard stores
    int r1c = r1 < M ? r1 : M - 1;

    short8 a0[4], a1[4];
    if (F32IN) {
        const float* Hf = (const float*)Hin;
#pragma unroll
        for (int s = 0; s < 4; s++) {          // k-step s covers k in [32s,32s+32)
            const float4* p0 = (const float4*)(Hf + (size_t)r0c * 128 + s * 32 + quad * 8);
            const float4* p1 = (const float4*)(Hf + (size_t)r1c * 128 + s * 32 + quad * 8);
            float4 f0 = p0[0], f1 = p0[1];
            float4 g0 = p1[0], g1 = p1[1];
            union { short8 s8; unsigned u[4]; } t0, t1;
            t0.u[0] = pack_bf16x2(f0.x, f0.y); t0.u[1] = pack_bf16x2(f0.z, f0.w);
            t0.u[2] = pack_bf16x2(f1.x, f1.y); t0.u[3] = pack_bf16x2(f1.z, f1.w);
            t1.u[0] = pack_bf16x2(g0.x, g0.y); t1.u[1] = pack_bf16x2(g0.z, g0.w);
            t1.u[2] = pack_bf16x2(g1.x, g1.y); t1.u[3] = pack_bf16x2(g1.z, g1.w);
            a0[s] = t0.s8; a1[s] = t1.s8;
        }
    } else {
        const unsigned* Hb = (const unsigned*)Hin;
#pragma unroll
        for (int s = 0; s < 4; s++) {
            a0[s] = *(const short8*)(Hb + (size_t)r0c * 64 + s * 16 + quad * 4);
            a1[s] = *(const short8*)(Hb + (size_t)r1c * 64 + s * 16 + quad * 4);
        }
    }
    f32x4 acc0[8], acc1[8];
#pragma unroll
    for (int t = 0; t < 8; t++) {
        acc0[t] = (f32x4){0.f, 0.f, 0.f, 0.f};
        acc1[t] = (f32x4){0.f, 0.f, 0.f, 0.f};
    }
#pragma unroll
    for (int s = 0; s < 4; s++) {
#pragma unroll
        for (int t = 0; t < 8; t++) {
            short8 b = *(const short8*)(WbT + (t * 16 + mrow) * 128 + s * 32 + quad * 8);
            acc0[t] = __builtin_amdgcn_mfma_f32_16x16x32_bf16(a0[s], b, acc0[t], 0, 0, 0);
            acc1[t] = __builtin_amdgcn_mfma_f32_16x16x32_bf16(a1[s], b, acc1[t], 0, 0, 0);
        }
    }
    // C/D layout: col = lane&15, row = quad*4 + reg.
    ushort* so = (ushort*)(sOut + wv * 32 * 64);
#pragma unroll
    for (int t = 0; t < 8; t++) {
#pragma unroll
        for (int r = 0; r < 4; r++) {
            int lr = quad * 4 + r;
            int c = t * 16 + mrow;
            so[lr * 128 + c] = bf16_1(acc0[t][r]);
            so[(lr + 16) * 128 + c] = bf16_1(acc1[t][r]);
        }
    }
    __syncthreads();
    const unsigned* si = sOut + wv * 32 * 64;
#pragma unroll 8
    for (int r = 0; r < 32; r++) {
        int row = m0 + r;
        if (row < M) O[(size_t)row * 64 + lane] = si[r * 64 + lane];
    }
}

// One block per graph: stream the sorted node segment, 4 waves stride it,
// LDS-combine (part = 512 floats), divide by count, write. No atomics.
__device__ __forceinline__ void pool_tile(const unsigned* __restrict__ HB,
                                          const int* __restrict__ gb,
                                          float* __restrict__ outp, int g,
                                          float* part) {
    int lane = threadIdx.x & 63, w = threadIdx.x >> 6;
    int s = gb[g], e = gb[g + 1];
    float ax = 0.f, ay = 0.f;
    for (int i = s + w; i < e; i += 4) {
        unsigned u = HB[(size_t)i * 64 + lane];
        ax += bf_lo(u); ay += bf_hi(u);
    }
    part[w * 128 + lane * 2] = ax;
    part[w * 128 + lane * 2 + 1] = ay;
    __syncthreads();
    if (threadIdx.x < 128) {
        float sum = part[threadIdx.x] + part[128 + threadIdx.x]
                  + part[256 + threadIdx.x] + part[384 + threadIdx.x];
        float c = (float)(e - s);
        outp[g * 128 + threadIdx.x] = sum / fmaxf(c, 1.0f);
    }
}

// ---- kernels --------------------------------------------------------------

// Pre-pass: graph bounds + W transpose+cast.
__global__ void k_prep(const int* __restrict__ batch, int* __restrict__ gb,
                       int G, int N,
                       const float* __restrict__ W0, const float* __restrict__ W1,
                       const float* __restrict__ W2, ushort* __restrict__ WbT) {
    int id = blockIdx.x * blockDim.x + threadIdx.x;
    if (id <= G) {
        int lo = 0, hi = N;
        while (lo < hi) { int mid = (lo + hi) >> 1; if (batch[mid] < id) lo = mid + 1; else hi = mid; }
        gb[id] = lo;
    }
    if (id < 3 * 16384) {
        int l = id >> 14;
        const float* W = (l == 0) ? W0 : ((l == 1) ? W1 : W2);
        int id2 = id & 16383;
        int n = id2 & 127, k = id2 >> 7;
        WbT[l * 16384 + n * 128 + k] = bf16_1(W[k * 128 + n]);
    }
}

// Heterogeneous: blocks[0..nbGemm) = layer-1 GEMM (fp32 x, in-reg bf16 cast);
// blocks[nbGemm..nbGemm+nbCount) = LDS histogram over nbGemm (=nbkt) coarse
// buckets (col>>7), 8192 edges/block, plain hist writes. NO global atomics.
__global__ __launch_bounds__(256) void k_phase1(const int* __restrict__ ei,
                                                int* __restrict__ hist, int E,
                                                const float* __restrict__ x,
                                                const ushort* __restrict__ WbT,
                                                unsigned* __restrict__ O, int M,
                                                int nbGemm, int nbCount) {
    __shared__ unsigned sBuf[8192];            // 32 KB (gemm epilogue / hist)
    if (blockIdx.x < nbGemm) {
        gemm_tile<true>(x, WbT, O, M, blockIdx.x, sBuf);
        return;
    }
    int blk = blockIdx.x - nbGemm;
    unsigned* hcnt = sBuf;                     // nbkt (<=784) counters
    int t = threadIdx.x;
    for (int i = t; i < nbGemm; i += 256) hcnt[i] = 0;
    __syncthreads();
    int base = blk * 8192;
    for (int i = t; i < 8192; i += 256) {
        int e = base + i;
        if (e < E) atomicAdd(&hcnt[(unsigned)ei[E + e] >> 7], 1u);  // LDS atomic
    }
    __syncthreads();
    for (int b = t; b < nbGemm; b += 256)      // bucket-major layout
        hist[b * nbCount + blk] = (int)hcnt[b];
}

// 1024-chunk exclusive scan: pre[i] = chunk-local exclusive prefix,
// bsum[chunk] = chunk total. n = nbkt*nbCount (~153K).
__global__ __launch_bounds__(1024) void k_scan1(const int* __restrict__ cnt,
                                                int* __restrict__ pre,
                                                int* __restrict__ bsum, int n) {
    __shared__ int wsum[16];
    int t = threadIdx.x, lane = t & 63, w = t >> 6;
    int i = blockIdx.x * 1024 + t;
    int v = (i < n) ? cnt[i] : 0;
    int x = v;
#pragma unroll
    for (int off = 1; off < 64; off <<= 1) {
        int y = __shfl_up(x, off, 64);
        if (lane >= off) x += y;
    }
    if (lane == 63) wsum[w] = x;
    __syncthreads();
    int woff = 0, tot = 0;
#pragma unroll
    for (int q = 0; q < 16; q++) { int s = wsum[q]; if (q < w) woff += s; tot += s; }
    if (i < n) pre[i] = woff + x - v;
    if (t == 0) bsum[blockIdx.x] = tot;
}

// Pass C: inline LDS scan of the (<=256) chunk sums; per-bucket bases into
// LDS; per-edge rank via LDS atomic; write packed records into bucket-
// contiguous regions. Block 0 also emits bucketStart[].
__global__ __launch_bounds__(256) void k_scat(const int* __restrict__ ei,
                                              const float* __restrict__ ew,
                                              const int* __restrict__ pre,
                                              const int* __restrict__ bsumRaw,
                                              int* __restrict__ bucketStart,
                                              int2* __restrict__ recs,
                                              int E, int nbkt, int nbCount,
                                              int nbScan) {
    __shared__ int sRaw[256];
    __shared__ int sPre[256];
    __shared__ int sWt[4];
    __shared__ int sBase[784];
    __shared__ unsigned rk[784];
    int t = threadIdx.x;
    sRaw[t] = (t < nbScan) ? bsumRaw[t] : 0;
    for (int b = t; b < nbkt; b += 256) rk[b] = 0;
    __syncthreads();
    int lane = t & 63, w2 = t >> 6;
    int v = sRaw[t];
    int x = v;
#pragma unroll
    for (int off = 1; off < 64; off <<= 1) {
        int y = __shfl_up(x, off, 64);
        if (lane >= off) x += y;
    }
    if (lane == 63) sWt[w2] = x;
    __syncthreads();
    int base = 0;
#pragma unroll
    for (int q = 0; q < 4; q++) { if (q < w2) base += sWt[q]; }
    sPre[t] = base + x - v;                    // exclusive prefix of chunk sums
    __syncthreads();
    int blk = blockIdx.x;
    for (int b = t; b < nbkt; b += 256) {
        int f = b * nbCount + blk;
        sBase[b] = pre[f] + sPre[f >> 10];     // this block's base in bucket b
    }
    if (blk == 0) {
        for (int b = t; b <= nbkt; b += 256) {
            if (b == nbkt) bucketStart[b] = E;
            else { int f = b * nbCount; bucketStart[b] = pre[f] + sPre[f >> 10]; }
        }
    }
    __syncthreads();
    int e0 = blk * 8192;
    for (int i = t; i < 8192; i += 256) {
        int e = e0 + i;
        if (e < E) {
            int r = ei[e];
            int c = ei[E + e];
            float w = ew[e];
            int b = (unsigned)c >> 7;
            unsigned rank = atomicAdd(&rk[b], 1u);      // LDS atomic
            int2 rec; rec.x = r | ((c & 127) << 17); rec.y = __float_as_int(w);
            recs[sBase[b] + (int)rank] = rec;
        }
    }
}

// Pass D: one block per bucket (128 nodes). Count + weighted degree in LDS;
// dinv = rsqrt(1 + wdeg); SELF-LOOP edge at each node's list head
// (y = dinv[c]; k_agg L1's *dinv[src] makes it dinv^2); ptr includes the
// self slot; in-bucket scatter with csr.y = w * dinv[c]. csr.x is stored
// PRE-SCALED as node*16 (uint4-row index) for k_agg's addressing (R16).
__global__ __launch_bounds__(256) void k_fin(const int2* __restrict__ recs,
                                             const int* __restrict__ bucketStart,
                                             int2* __restrict__ csr,
                                             int* __restrict__ ptrv,
                                             float* __restrict__ dinv,
                                             int N, int nbkt) {
    __shared__ unsigned scnt[128];
    __shared__ float swdeg[128];
    __shared__ float sdinv[128];
    __shared__ unsigned sTot0;
    int t = threadIdx.x;
    int b = blockIdx.x;
    int e0 = bucketStart[b], e1 = bucketStart[b + 1];
    int FB = e0 + b * 128;                     // final base incl. prior selfs
    if (t < 128) { scnt[t] = 0u; swdeg[t] = 0.f; }
    __syncthreads();
    for (int i = e0 + t; i < e1; i += 256) {
        int2 rec = recs[i];
        int cl = (rec.x >> 17) & 127;
        atomicAdd(&scnt[cl], 1u);                       // LDS atomic
        atomicAdd(&swdeg[cl], __int_as_float(rec.y));   // LDS f32 atomic
    }
    __syncthreads();
    unsigned myc = (t < 128) ? scnt[t] : 0u;
    int lane = t & 63, wv = t >> 6;
    unsigned inc = myc;
#pragma unroll
    for (int off = 1; off < 64; off <<= 1) {
        unsigned y = __shfl_up(inc, off, 64);
        if (lane >= off) inc += y;
    }
    if (t == 63) sTot0 = inc;                  // wave-0 total
    __syncthreads();
    unsigned excl = inc - myc + ((wv == 1) ? sTot0 : 0u);
    if (t < 128) {
        float dv = rsqrtf(1.0f + swdeg[t]);
        sdinv[t] = dv;
        scnt[t] = excl + (unsigned)t + 1u;     // scatter cursor (rel. to FB)
        int node = b * 128 + t;
        int start = FB + (int)excl + t;
        if (node < N) {
            ptrv[node] = start;
            dinv[node] = dv;
            int2 sv; sv.x = node << 4;         // self: w=1*dinv[c], scaled idx
            sv.y = __float_as_int(dv);
            csr[start] = sv;
        }
    }
    if (b == nbkt - 1 && t == 0) ptrv[N] = e1 + N;  // = E + N
    __syncthreads();
    for (int i = e0 + t; i < e1; i += 256) {
        int2 rec = recs[i];
        int cl = (rec.x >> 17) & 127;
        int r = rec.x & 131071;
        unsigned rank = atomicAdd(&scnt[cl], 1u);       // LDS atomic
        float y = __int_as_float(rec.y) * sdinv[cl];
        int2 mv; mv.x = r << 4; mv.y = __float_as_int(y);
        csr[FB + (int)rank] = mv;
    }
}

// One wave per node, uniform edge list (self-loop is edge 0). QUAD-EDGE
// uint4 gather (R16): lane = (grp = lane>>4 in 0..3, q = lane&15). One
// wave-level load covers 4 edges x 16B/lane; each lane accumulates 8
// features (8q..8q+7). csr.x is the pre-scaled uint4-row index (node*16),
// so addr = m.x + q (one 32-bit add). NORM (layer 1): csr.y *= dinv[src]
// on first use, written back (each entry owned by one wave; race-free).
template <bool NORM>
__global__ __launch_bounds__(256) void k_agg(const unsigned* __restrict__ HL,
                                             const int* __restrict__ ptr,
                                             int2* __restrict__ csr,
                                             const float* __restrict__ dinv,
                                             const float* __restrict__ bias,
                                             unsigned* __restrict__ Hout, int M) {
    __shared__ int2 sM[4 * 64];
    int node = (int)((blockIdx.x * blockDim.x + threadIdx.x) >> 6);
    if (node >= M) return;
    int lane = threadIdx.x & 63;
    int grp = lane >> 4;                  // edge subgroup 0..3
    int q = lane & 15;                    // features 8q .. 8q+7 (one uint4)
    int2* mbase = &sM[(threadIdx.x >> 6) * 64];
    int e0 = ptr[node], e1 = ptr[node + 1];
    int deg = e1 - e0;                    // includes self edge
    int nbv = deg < 64 ? deg : 64;
    if (lane < nbv) {
        int2 m = csr[e0 + lane];          // one coalesced load
        if (NORM) {
            m.y = __float_as_int(__int_as_float(m.y) * dinv[m.x >> 4]);
            csr[e0 + lane] = m;           // finalize for layers 2/3
        }
        mbase[lane] = m;
    }
    const uint4* HL4 = (const uint4*)HL;  // row = 16 uint4
    float a0 = 0.f, a1 = 0.f, a2 = 0.f, a3 = 0.f;
    float a4 = 0.f, a5 = 0.f, a6 = 0.f, a7 = 0.f;
    int j = grp;
    for (; j + 16 <= nbv; j += 16) {      // 4 quads (16 edges) in flight
        int2 m[4]; uint4 u[4];
#pragma unroll
        for (int t = 0; t < 4; t++) m[t] = mbase[j + 4 * t];
#pragma unroll
        for (int t = 0; t < 4; t++) u[t] = HL4[(unsigned)(m[t].x + q)];
#pragma unroll
        for (int t = 0; t < 4; t++) {
            float nv = __int_as_float(m[t].y);
            a0 += nv * bf_lo(u[t].x); a1 += nv * bf_hi(u[t].x);
            a2 += nv * bf_lo(u[t].y); a3 += nv * bf_hi(u[t].y);
            a4 += nv * bf_lo(u[t].z); a5 += nv * bf_hi(u[t].z);
            a6 += nv * bf_lo(u[t].w); a7 += nv * bf_hi(u[t].w);
        }
    }
    for (; j < nbv; j += 4) {             // remainder quads
        int2 m = mbase[j];
        uint4 u = HL4[(unsigned)(m.x + q)];
        float nv = __int_as_float(m.y);
        a0 += nv * bf_lo(u.x); a1 += nv * bf_hi(u.x);
        a2 += nv * bf_lo(u.y); a3 += nv * bf_hi(u.y);
        a4 += nv * bf_lo(u.z); a5 += nv * bf_hi(u.z);
        a6 += nv * bf_lo(u.w); a7 += nv * bf_hi(u.w);
    }
    for (int e = e0 + 64 + grp; e < e1; e += 4) {  // rare high-degree tail
        int2 m = csr[e];
        if (NORM) {
            m.y = __float_as_int(__int_as_float(m.y) * dinv[m.x >> 4]);
            csr[e] = m;
        }
        uint4 u = HL4[(unsigned)(m.x + q)];
        float nv = __int_as_float(m.y);
        a0 += nv * bf_lo(u.x); a1 += nv * bf_hi(u.x);
        a2 += nv * bf_lo(u.y); a3 += nv * bf_hi(u.y);
        a4 += nv * bf_lo(u.z); a5 += nv * bf_hi(u.z);
        a6 += nv * bf_lo(u.w); a7 += nv * bf_hi(u.w);
    }
    // combine the 4 edge subgroups (grp 0<->2,1<->3 then 0<->1,2<->3)
    a0 += __shfl_xor(a0, 32, 64); a1 += __shfl_xor(a1, 32, 64);
    a2 += __shfl_xor(a2, 32, 64); a3 += __shfl_xor(a3, 32, 64);
    a4 += __shfl_xor(a4, 32, 64); a5 += __shfl_xor(a5, 32, 64);
    a6 += __shfl_xor(a6, 32, 64); a7 += __shfl_xor(a7, 32, 64);
    a0 += __shfl_xor(a0, 16, 64); a1 += __shfl_xor(a1, 16, 64);
    a2 += __shfl_xor(a2, 16, 64); a3 += __shfl_xor(a3, 16, 64);
    a4 += __shfl_xor(a4, 16, 64); a5 += __shfl_xor(a5, 16, 64);
    a6 += __shfl_xor(a6, 16, 64); a7 += __shfl_xor(a7, 16, 64);
    if (grp == 0) {
        const float4* b4 = (const float4*)bias;
        float4 bA = b4[2 * q], bB = b4[2 * q + 1];
        float r0 = fmaxf(a0 + bA.x, 0.f);
        float r1 = fmaxf(a1 + bA.y, 0.f);
        float r2 = fmaxf(a2 + bA.z, 0.f);
        float r3 = fmaxf(a3 + bA.w, 0.f);
        float r4 = fmaxf(a4 + bB.x, 0.f);
        float r5 = fmaxf(a5 + bB.y, 0.f);
        float r6 = fmaxf(a6 + bB.z, 0.f);
        float r7 = fmaxf(a7 + bB.w, 0.f);
        uint4 pv;
        pv.x = pack_bf16x2(r0, r1);
        pv.y = pack_bf16x2(r2, r3);
        pv.z = pack_bf16x2(r4, r5);
        pv.w = pack_bf16x2(r6, r7);
        ((uint4*)(Hout + (size_t)node * 64))[q] = pv;
    }
}

// Heterogeneous: blocks[0..nbGemm) = next-layer GEMM reading Hb;
// blocks[nbGemm..nbGemm+G) = pool of the SAME Hb into outp (both depend only
// on the preceding agg). nbGemm=0 -> pool-only (final layer).
__global__ __launch_bounds__(256) void k_gemm_pool(const unsigned* __restrict__ Hb,
                                                   const ushort* __restrict__ WbT,
                                                   unsigned* __restrict__ O, int M,
                                                   const int* __restrict__ gb,
                                                   float* __restrict__ outp,
                                                   int nbGemm) {
    __shared__ unsigned sBuf[8192];            // gemm epilogue / pool partials
    if (blockIdx.x < nbGemm) {
        gemm_tile<false>(Hb, WbT, O, M, blockIdx.x, sBuf);
        return;
    }
    pool_tile(Hb, gb, outp, blockIdx.x - nbGemm, (float*)sBuf);
}

extern "C" void kernel_launch(void* const* d_in, const int* in_sizes, int n_in,
                              void* d_out, int out_size, void* d_ws, size_t ws_size,
                              hipStream_t stream) {
    const float* x     = (const float*)d_in[0];
    const int*   ei    = (const int*)d_in[1];
    const float* ew    = (const float*)d_in[2];
    const int*   batch = (const int*)d_in[3];
    const float* Wt[3] = {(const float*)d_in[4], (const float*)d_in[6], (const float*)d_in[8]};
    const float* bt[3] = {(const float*)d_in[5], (const float*)d_in[7], (const float*)d_in[9]};
    float* out = (float*)d_out;

    const int D = 128;
    const int N = in_sizes[0] / D;       // 100000
    const int E = in_sizes[2];           // 1600000
    const int G = out_size / (3 * D);    // 256

    // workspace carve-up (256 B aligned)
    char* p = (char*)d_ws;
    auto alloc = [&](size_t bytes) {
        void* r = (void*)p;
        p += (bytes + 255) & ~(size_t)255;
        return r;
    };
    int nbkt    = (N + 127) / 128;              // 782 coarse buckets (== nbGemm)
    int nbCount = (E + 8191) / 8192;            // 196 histogram blocks
    int F       = nbkt * nbCount;               // 153272 scan elements
    int nbScan  = (F + 1023) / 1024;            // 150 (<=256 for inline scan)

    int*      ptr    = (int*)alloc((size_t)(N + 1) * 4);
    int*      bsum   = (int*)alloc((size_t)256 * 4);
    int*      gb     = (int*)alloc((size_t)(G + 1) * 4);
    int*      bstart = (int*)alloc((size_t)(nbkt + 1) * 4);
    float*    dinv   = (float*)alloc((size_t)N * 4);
    ushort*   WbT    = (ushort*)alloc((size_t)3 * 16384 * 2);
    int2*     csr    = (int2*)alloc((size_t)(E + N) * 8);     // incl. selfs
    unsigned* bufA   = (unsigned*)alloc((size_t)N * 64 * 4);  // hl ping
    unsigned* bufB   = (unsigned*)alloc((size_t)N * 64 * 4);  // h / hl pong
    // aliases: hist+pre live only before k_fin writes csr; recs dead before
    // k_agg L1 writes bufB.
    int*  hist = (int*)csr;                    // F ints (613 KB)
    int*  pre  = hist + F;                     // F ints
    int2* recs = (int2*)bufB;                  // E int2 (12.8 MB)

    int nbGemm = nbkt;                          // 782 gemm blocks
    int prepWork = 3 * 16384;

    k_prep<<<(prepWork + 255) / 256, 256, 0, stream>>>(batch, gb, G, N,
                                                       Wt[0], Wt[1], Wt[2], WbT);
    // layer-1 GEMM fused with the histogram pass (independent inputs)
    k_phase1<<<nbGemm + nbCount, 256, 0, stream>>>(ei, hist, E, x, WbT,
                                                   bufA, N, nbGemm, nbCount);
    k_scan1<<<nbScan, 1024, 0, stream>>>(hist, pre, bsum, F);
    k_scat<<<nbCount, 256, 0, stream>>>(ei, ew, pre, bsum, bstart, recs,
                                        E, nbkt, nbCount, nbScan);
    k_fin<<<nbkt, 256, 0, stream>>>(recs, bstart, csr, ptr, dinv, N, nbkt);

    // L1 aggregate (finalizes csr.y *= dinv[src] in-flight), then fused
    // (gemm_{l+1} + pool_l), final pool-only.
    k_agg<true><<<(N + 3) / 4, 256, 0, stream>>>(bufA, ptr, csr, dinv, bt[0],
                                                 bufB, N);
    k_gemm_pool<<<nbGemm + G, 256, 0, stream>>>(bufB, WbT + 16384, bufA, N,
                                                gb, out + 0 * (size_t)G * D, nbGemm);
    k_agg<false><<<(N + 3) / 4, 256, 0, stream>>>(bufA, ptr, csr, dinv, bt[1],
                                                  bufB, N);
    k_gemm_pool<<<nbGemm + G, 256, 0, stream>>>(bufB, WbT + 2 * 16384, bufA, N,
                                                gb, out + 1 * (size_t)G * D, nbGemm);
    k_agg<false><<<(N + 3) / 4, 256, 0, stream>>>(bufA, ptr, csr, dinv, bt[2],
                                                  bufB, N);
    k_gemm_pool<<<G, 256, 0, stream>>>(bufB, WbT, nullptr, 0,
                                       gb, out + 2 * (size_t)G * D, 0);
}